// Round 7
// baseline (68.864 us; speedup 1.0000x reference)
//
#include <hip/hip_runtime.h>
#include <math.h>

// Problem constants (from setup_inputs: B=128, N=512, C=64)
#define BB 128
#define NN 512
#define CC 64
#define FS 16
#define RES 497          // N - FS + 1
#define MAXP 256         // ceil(N * 0.5)
#define BN (BB*NN)       // 65536
#define GT (BB*RES*FS)   // 1017856
#define WPB 16           // windows per block (passA)
#define NCH 32           // ceil(RES/WPB)
#define ROWS (WPB+FS-1)  // 31 rows staged per block
#define PITCH 66         // float pitch: 8B-aligned rows, bank stride 2 -> worst 2-way (free)
#define GWIN 64          // windows per k_gumbel block
#define GBLK 8           // ceil(RES/GWIN)

// ---------------- Threefry-2x32 (JAX key (0,777), partitionable) ----------------
__device__ __forceinline__ unsigned rotl32(unsigned x, int d){ return (x<<d)|(x>>(32-d)); }

__device__ __forceinline__ void threefry777(unsigned x0, unsigned x1, unsigned &o0, unsigned &o1){
  const unsigned ks0 = 0u, ks1 = 777u;
  const unsigned ks2 = 0x1BD11BDAu ^ ks0 ^ ks1;
  x0 += ks0; x1 += ks1;
  x0+=x1; x1=rotl32(x1,13); x1^=x0;
  x0+=x1; x1=rotl32(x1,15); x1^=x0;
  x0+=x1; x1=rotl32(x1,26); x1^=x0;
  x0+=x1; x1=rotl32(x1, 6); x1^=x0;
  x0+=ks1; x1+=ks2+1u;
  x0+=x1; x1=rotl32(x1,17); x1^=x0;
  x0+=x1; x1=rotl32(x1,29); x1^=x0;
  x0+=x1; x1=rotl32(x1,16); x1^=x0;
  x0+=x1; x1=rotl32(x1,24); x1^=x0;
  x0+=ks2; x1+=ks0+2u;
  x0+=x1; x1=rotl32(x1,13); x1^=x0;
  x0+=x1; x1=rotl32(x1,15); x1^=x0;
  x0+=x1; x1=rotl32(x1,26); x1^=x0;
  x0+=x1; x1=rotl32(x1, 6); x1^=x0;
  x0+=ks0; x1+=ks1+3u;
  x0+=x1; x1=rotl32(x1,17); x1^=x0;
  x0+=x1; x1=rotl32(x1,29); x1^=x0;
  x0+=x1; x1=rotl32(x1,16); x1^=x0;
  x0+=x1; x1=rotl32(x1,24); x1^=x0;
  x0+=ks1; x1+=ks2+4u;
  x0+=x1; x1=rotl32(x1,13); x1^=x0;
  x0+=x1; x1=rotl32(x1,15); x1^=x0;
  x0+=x1; x1=rotl32(x1,26); x1^=x0;
  x0+=x1; x1=rotl32(x1, 6); x1^=x0;
  x0+=ks2; x1+=ks0+5u;
  o0 = x0; o1 = x1;
}

// Gumbel element p of flat (B,RES,FS): partitionable counter (0,p), bits=o0^o1,
// f32 uniform->gumbel (reference dtype), promoted to f64 at use site.
__device__ __forceinline__ float gumbel_at_f32(unsigned p){
  unsigned o0, o1;
  threefry777(0u, p, o0, o1);
  unsigned bits = o0 ^ o1;
  float fl = __uint_as_float((bits >> 9) | 0x3f800000u) - 1.0f;  // [0,1)
  float u  = fmaxf(1.17549435e-38f, fl);
  return -logf(-logf(u));
}

// push v to lane dstLane (0..63) within wave (ds_permute, all lanes must be active)
__device__ __forceinline__ double wave_push_f64(double v, int dstLane){
  int lo = __double2loint(v), hi = __double2hiint(v);
  int plo = __builtin_amdgcn_ds_permute(dstLane<<2, lo);
  int phi = __builtin_amdgcn_ds_permute(dstLane<<2, hi);
  return __hiloint2double(phi, plo);
}

// ---------------- K1: fused scores + stable descending bitonic argsort per graph ----------
__global__ __launch_bounds__(NN) void k_scoresort(const float* __restrict__ x,
    const float* __restrict__ w, const float* __restrict__ bsc,
    const float* __restrict__ att, double* __restrict__ s1s,
    double* __restrict__ s2s, int* __restrict__ perm){
  int b = blockIdx.x, t = threadIdx.x;
  __shared__ double ss[NN];
  __shared__ int    si[NN];
  __shared__ double l1[NN], l2[NN];

  double wn=0.0, dw=0.0, d1=0.0, d2=0.0;
  #pragma unroll
  for (int c=0;c<CC;c++){ double wv=(double)w[c]; wn += wv*wv; }
  const float4* xr = (const float4*)(x + (size_t)(b*NN+t)*CC);
  #pragma unroll
  for (int q=0;q<CC/4;q++){
    float4 v = xr[q];
    double xv;
    xv=(double)v.x; dw+=xv*(double)w[4*q+0]; d1+=xv*(double)att[4*q+0]; d2+=xv*(double)att[CC+4*q+0];
    xv=(double)v.y; dw+=xv*(double)w[4*q+1]; d1+=xv*(double)att[4*q+1]; d2+=xv*(double)att[CC+4*q+1];
    xv=(double)v.z; dw+=xv*(double)w[4*q+2]; d1+=xv*(double)att[4*q+2]; d2+=xv*(double)att[CC+4*q+2];
    xv=(double)v.w; dw+=xv*(double)w[4*q+3]; d1+=xv*(double)att[4*q+3]; d2+=xv*(double)att[CC+4*q+3];
  }
  double s = (dw + (double)bsc[0]) / sqrt(wn);
  int idx = t;
  l1[t] = d1;
  l2[t] = d2;

  // before(a,b) = (a.s > b.s) || (a.s == b.s && a.i < b.i)  — total order (idx unique)
  for (int k = 2; k <= NN; k <<= 1){
    bool up = ((t & k) == 0);
    // cross-wave stages via LDS
    for (int j = k >> 1; j >= 64; j >>= 1){
      ss[t] = s; si[t] = idx;
      __syncthreads();
      double os = ss[t ^ j]; int oi = si[t ^ j];
      bool first = ((t & j) == 0);
      bool cmp = (s > os) || (s == os && idx < oi);
      bool keep = (cmp == (first == up));
      if (!keep){ s = os; idx = oi; }
      __syncthreads();
    }
    // in-wave stages via register shuffles
    #pragma unroll
    for (int j = 32; j > 0; j >>= 1){
      if (j <= (k >> 1)){
        double os = __shfl_xor(s, j, 64);
        int    oi = __shfl_xor(idx, j, 64);
        bool first = ((t & j) == 0);
        bool cmp = (s > os) || (s == os && idx < oi);
        bool keep = (cmp == (first == up));
        if (!keep){ s = os; idx = oi; }
      }
    }
  }
  __syncthreads();
  perm[b*NN + t] = idx;
  s1s[b*NN + t] = l1[idx];  // sorted-order a1 dot
  s2s[b*NN + t] = l2[idx];  // sorted-order a2 dot
}

// ---------------- K2: passA, 16 lanes = 1 window: gk, rank, colsum partial ----------------
__global__ __launch_bounds__(256) void k_passA(const float* __restrict__ x,
    const int* __restrict__ perm, const double* __restrict__ s1s,
    const double* __restrict__ s2s, double* __restrict__ gkd,
    unsigned char* __restrict__ rank8, double* __restrict__ partial){
  int b = blockIdx.y, ch = blockIdx.x, tid = threadIdx.x;
  int i0 = ch*WPB;
  int nwin  = min(WPB, RES - i0);
  int nrows = min(ROWS, NN - i0);
  __shared__ float  xs[ROWS*PITCH];   // ~8.2 KB
  __shared__ int    pg[ROWS];
  __shared__ double wred[4][FS];

  if (tid < nrows) pg[tid] = perm[b*NN + i0 + tid];
  __syncthreads();
  for (int u = tid; u < nrows*16; u += 256){
    int r = u >> 4, seg = u & 15;
    float4 v = ((const float4*)(x + (size_t)(b*NN + pg[r])*CC))[seg];
    float2* dst = (float2*)&xs[r*PITCH + seg*4];
    dst[0] = make_float2(v.x, v.y);
    dst[1] = make_float2(v.z, v.w);
  }
  __syncthreads();

  int w = tid >> 4, j = tid & 15;
  int lane = tid & 63, gbase = lane & 48, wv = tid >> 6;
  bool act = (w < nwin);
  int i = i0 + w;

  // squared distance (f64, sequential c order like the reference)
  double sq = 0.0;
  const float* rs = &xs[w*PITCH];
  const float* rd = &xs[(w+j)*PITCH];
  #pragma unroll
  for (int c2=0;c2<CC/2;c2++){
    float2 a  = *(const float2*)&rs[2*c2];
    float2 bb = *(const float2*)&rd[2*c2];
    double d0 = (double)a.x - (double)bb.x;
    double d1v= (double)a.y - (double)bb.y;
    sq += d0*d0;
    sq += d1v*d1v;
  }
  double d   = (sq > 0.0) ? sqrt(sq) : 0.0;     // safe_norm
  double gkv = exp(-d*0.5) - 1e-20;

  // window softmax term (f64, max-subtracted)
  int drow = min(i + j, NN-1);                   // clamp only hits inactive lanes
  double smt = s1s[b*NN + i] + s2s[b*NN + drow];
  double m = smt;
  #pragma unroll
  for (int off=8; off; off>>=1) m = fmax(m, __shfl_xor(m, off, 16));
  double em = exp(smt - m);
  double ssum = em;
  #pragma unroll
  for (int off=8; off; off>>=1) ssum += __shfl_xor(ssum, off, 16);
  double smn = em / ssum;

  // rank within window: #(k before j) under (gk desc, idx asc)
  int rank = 0;
  #pragma unroll
  for (int k=0;k<16;k++){
    double gkk = __shfl(gkv, gbase + k, 64);
    rank += ((gkk > gkv) || (gkk == gkv && k < j)) ? 1 : 0;
  }

  if (act){
    size_t base = ((size_t)b*RES + i)*FS;
    gkd[base + j]   = gkv;
    rank8[base + j] = (unsigned char)rank;
  }

  // scatter softmax term to its rank lane, then sum windows (deterministic order)
  double contrib = act ? smn : 0.0;
  double srt = wave_push_f64(contrib, gbase + rank);
  srt += __shfl_xor(srt, 16, 64);
  srt += __shfl_xor(srt, 32, 64);
  if (lane < FS) wred[wv][lane] = srt;
  __syncthreads();
  if (tid < FS){
    partial[((size_t)b*NCH + ch)*FS + tid] =
        wred[0][tid] + wred[1][tid] + wred[2][tid] + wred[3][tid];
  }
}

// ---------------- K3: wide gumbel: colsum (redundant per block) + gumbel-softmax,
//                      ths, shifted, delta.  grid = (GBLK, BB) ----------------
__global__ __launch_bounds__(1024) void k_gumbel(const double* __restrict__ gkd,
    const unsigned char* __restrict__ rank8, const double* __restrict__ partial,
    const int* __restrict__ epoch_p, float* __restrict__ shifted_out,
    int* __restrict__ delta){
  int b = blockIdx.y, tid = threadIdx.x;
  int win = blockIdx.x*GWIN + (tid >> 4);
  int s = tid & 15;
  int lane = tid & 63, gbase = lane & 48;
  __shared__ double pl[NCH*FS];     // 4 KB
  __shared__ double cs[FS];

  if (tid < NCH*FS) pl[tid] = partial[(size_t)b*NCH*FS + tid];
  __syncthreads();
  if (tid < FS){
    double a = 0.0;
    #pragma unroll
    for (int ch=0; ch<NCH; ch++) a += pl[ch*FS + tid];   // same seq order as before
    cs[tid] = a;
  }
  __syncthreads();

  if (win >= RES) return;
  double tau = 10.0 * pow(0.01, (double)epoch_p[0] / 100.0);
  size_t base = ((size_t)b*RES + win)*FS;

  double z;
  if (s == 0) z = -(double)INFINITY;
  else {
    double g = (double)gumbel_at_f32((unsigned)(base + (unsigned)s));
    z = (g + cs[s]) / tau;
  }
  double m = z;
  #pragma unroll
  for (int off=8; off; off>>=1) m = fmax(m, __shfl_xor(m, off, 16));
  double e = (s == 0) ? 0.0 : exp(z - m);
  double ssum = e;
  #pragma unroll
  for (int off=8; off; off>>=1) ssum += __shfl_xor(ssum, off, 16);
  double gmb = e / ssum;

  double gkv = gkd[base + s];
  int rk = rank8[base + s];
  double gmbr = __shfl(gmb, gbase + rk, 64);   // gmb at my rank position
  double ths = gkv * gmbr;
  #pragma unroll
  for (int off=8; off; off>>=1) ths += __shfl_xor(ths, off, 16);

  double shv = fmax(gkv - ths, 0.0);
  shifted_out[base + s] = (float)shv;

  double av = (s == 0) ? (double)INFINITY : shv;   // argmin over j=1..15, first-min wins
  int ai = s;
  #pragma unroll
  for (int off=8; off; off>>=1){
    double ov = __shfl_xor(av, off, 16);
    int    oi = __shfl_xor(ai, off, 16);
    if (ov < av || (ov == av && oi < ai)){ av = ov; ai = oi; }
  }
  if (s == 0) delta[b*RES + win] = ai;
}

// ---------------- K4: per-graph chain (pointer doubling) + pooled gather ----------------
__global__ __launch_bounds__(256) void k_chainpool(const int* __restrict__ delta,
    const int* __restrict__ perm, const float* __restrict__ x,
    float* __restrict__ piv_out, float* __restrict__ pooled){
  int b = blockIdx.x, tid = threadIdx.x;
  __shared__ int tbl[8][512];    // 16 KB
  __shared__ int pivS[MAXP];

  for (int i = tid; i < 512; i += 256){
    int v;
    if (i < RES){ v = i + delta[b*RES + i]; if (v > RES) v = RES; }
    else v = RES;                 // absorbing sentinel
    tbl[0][i] = v;
  }
  __syncthreads();
  #pragma unroll
  for (int k=1;k<8;k++){
    int v0 = tbl[k-1][tid];
    int v1 = tbl[k-1][tid+256];
    tbl[k][tid]     = tbl[k-1][v0];
    tbl[k][tid+256] = tbl[k-1][v1];
    __syncthreads();
  }
  {
    int p = 0;
    #pragma unroll
    for (int k=0;k<8;k++) if ((tid>>k)&1) p = tbl[k][p];
    int piv = (p < RES) ? p : -1;
    pivS[tid] = piv;
    piv_out[b*MAXP + tid] = (float)piv;
  }
  __syncthreads();

  // pooled gather (masked)
  for (int u = tid; u < MAXP*16; u += 256){
    int bp = u >> 4, seg = u & 15;
    int piv = pivS[bp];
    float4 v = make_float4(0.f,0.f,0.f,0.f);
    if (piv >= 0){
      int src = perm[b*NN + piv];
      v = ((const float4*)(x + (size_t)(b*NN + src)*CC))[seg];
    }
    ((float4*)pooled)[(size_t)(b*MAXP + bp)*16 + seg] = v;
  }
}

extern "C" void kernel_launch(void* const* d_in, const int* in_sizes, int n_in,
                              void* d_out, int out_size, void* d_ws, size_t ws_size,
                              hipStream_t stream) {
  (void)in_sizes; (void)n_in; (void)out_size; (void)ws_size;
  const float* x    = (const float*)d_in[0];
  const float* w    = (const float*)d_in[1];
  const float* bsc  = (const float*)d_in[2];
  const float* att  = (const float*)d_in[3];
  const int*   epch = (const int*)d_in[5];

  // workspace layout (~11.3 MiB), f64 first for alignment
  double* s1s     = (double*)d_ws;               // BN
  double* s2s     = s1s + BN;                    // BN
  double* gkd     = s2s + BN;                    // GT
  double* partial = gkd + GT;                    // BB*NCH*FS
  int*    perm    = (int*)(partial + (size_t)BB*NCH*FS); // BN
  int*    delta   = perm + BN;                   // BB*RES
  unsigned char* rank8 = (unsigned char*)(delta + BB*RES); // GT bytes

  float* out_pooled  = (float*)d_out;                   // B*MAXP*C
  float* out_shifted = out_pooled + BB*MAXP*CC;         // B*RES*FS
  float* out_piv     = out_shifted + (size_t)BB*RES*FS; // B*MAXP (as float)

  k_scoresort<<<BB, NN, 0, stream>>>(x, w, bsc, att, s1s, s2s, perm);
  k_passA    <<<dim3(NCH, BB), 256, 0, stream>>>(x, perm, s1s, s2s, gkd, rank8, partial);
  k_gumbel   <<<dim3(GBLK, BB), 1024, 0, stream>>>(gkd, rank8, partial, epch, out_shifted, delta);
  k_chainpool<<<BB, 256, 0, stream>>>(delta, perm, x, out_piv, out_pooled);
}

// Round 8
// 62.286 us; speedup vs baseline: 1.1056x; 1.1056x over previous
//
#include <hip/hip_runtime.h>
#include <math.h>

// Problem constants (from setup_inputs: B=128, N=512, C=64)
#define BB 128
#define NN 512
#define CC 64
#define FS 16
#define RES 497          // N - FS + 1
#define MAXP 256         // ceil(N * 0.5)
#define BN (BB*NN)       // 65536
#define GT (BB*RES*FS)   // 1017856
#define WPB 16           // windows per block (passA)
#define NCH 32           // ceil(RES/WPB)
#define ROWS (WPB+FS-1)  // 31 rows staged per block
#define PITCH 66         // float pitch: 8B-aligned rows, bank stride 2 -> worst 2-way (free)
#define GW2 256          // windows per k_gumbel block (serial-thread version)

// ---------------- Threefry-2x32 (JAX key (0,777), partitionable) ----------------
__device__ __forceinline__ unsigned rotl32(unsigned x, int d){ return (x<<d)|(x>>(32-d)); }

__device__ __forceinline__ void threefry777(unsigned x0, unsigned x1, unsigned &o0, unsigned &o1){
  const unsigned ks0 = 0u, ks1 = 777u;
  const unsigned ks2 = 0x1BD11BDAu ^ ks0 ^ ks1;
  x0 += ks0; x1 += ks1;
  x0+=x1; x1=rotl32(x1,13); x1^=x0;
  x0+=x1; x1=rotl32(x1,15); x1^=x0;
  x0+=x1; x1=rotl32(x1,26); x1^=x0;
  x0+=x1; x1=rotl32(x1, 6); x1^=x0;
  x0+=ks1; x1+=ks2+1u;
  x0+=x1; x1=rotl32(x1,17); x1^=x0;
  x0+=x1; x1=rotl32(x1,29); x1^=x0;
  x0+=x1; x1=rotl32(x1,16); x1^=x0;
  x0+=x1; x1=rotl32(x1,24); x1^=x0;
  x0+=ks2; x1+=ks0+2u;
  x0+=x1; x1=rotl32(x1,13); x1^=x0;
  x0+=x1; x1=rotl32(x1,15); x1^=x0;
  x0+=x1; x1=rotl32(x1,26); x1^=x0;
  x0+=x1; x1=rotl32(x1, 6); x1^=x0;
  x0+=ks0; x1+=ks1+3u;
  x0+=x1; x1=rotl32(x1,17); x1^=x0;
  x0+=x1; x1=rotl32(x1,29); x1^=x0;
  x0+=x1; x1=rotl32(x1,16); x1^=x0;
  x0+=x1; x1=rotl32(x1,24); x1^=x0;
  x0+=ks1; x1+=ks2+4u;
  x0+=x1; x1=rotl32(x1,13); x1^=x0;
  x0+=x1; x1=rotl32(x1,15); x1^=x0;
  x0+=x1; x1=rotl32(x1,26); x1^=x0;
  x0+=x1; x1=rotl32(x1, 6); x1^=x0;
  x0+=ks2; x1+=ks0+5u;
  o0 = x0; o1 = x1;
}

// Gumbel element p of flat (B,RES,FS): partitionable counter (0,p), bits=o0^o1,
// f32 uniform->gumbel (reference dtype), promoted to f64 at use site.
__device__ __forceinline__ float gumbel_at_f32(unsigned p){
  unsigned o0, o1;
  threefry777(0u, p, o0, o1);
  unsigned bits = o0 ^ o1;
  float fl = __uint_as_float((bits >> 9) | 0x3f800000u) - 1.0f;  // [0,1)
  float u  = fmaxf(1.17549435e-38f, fl);
  return -logf(-logf(u));
}

// push v to lane dstLane (0..63) within wave (ds_permute, all lanes must be active)
__device__ __forceinline__ double wave_push_f64(double v, int dstLane){
  int lo = __double2loint(v), hi = __double2hiint(v);
  int plo = __builtin_amdgcn_ds_permute(dstLane<<2, lo);
  int phi = __builtin_amdgcn_ds_permute(dstLane<<2, hi);
  return __hiloint2double(phi, plo);
}

// ---------------- K1: fused scores + stable descending bitonic argsort per graph ----------
__global__ __launch_bounds__(NN) void k_scoresort(const float* __restrict__ x,
    const float* __restrict__ w, const float* __restrict__ bsc,
    const float* __restrict__ att, double* __restrict__ s1s,
    double* __restrict__ s2s, int* __restrict__ perm){
  int b = blockIdx.x, t = threadIdx.x;
  __shared__ double ss[NN];
  __shared__ int    si[NN];
  __shared__ double l1[NN], l2[NN];

  double wn=0.0, dw=0.0, d1=0.0, d2=0.0;
  #pragma unroll
  for (int c=0;c<CC;c++){ double wv=(double)w[c]; wn += wv*wv; }
  const float4* xr = (const float4*)(x + (size_t)(b*NN+t)*CC);
  #pragma unroll
  for (int q=0;q<CC/4;q++){
    float4 v = xr[q];
    double xv;
    xv=(double)v.x; dw+=xv*(double)w[4*q+0]; d1+=xv*(double)att[4*q+0]; d2+=xv*(double)att[CC+4*q+0];
    xv=(double)v.y; dw+=xv*(double)w[4*q+1]; d1+=xv*(double)att[4*q+1]; d2+=xv*(double)att[CC+4*q+1];
    xv=(double)v.z; dw+=xv*(double)w[4*q+2]; d1+=xv*(double)att[4*q+2]; d2+=xv*(double)att[CC+4*q+2];
    xv=(double)v.w; dw+=xv*(double)w[4*q+3]; d1+=xv*(double)att[4*q+3]; d2+=xv*(double)att[CC+4*q+3];
  }
  double s = (dw + (double)bsc[0]) / sqrt(wn);
  int idx = t;
  l1[t] = d1;
  l2[t] = d2;

  // before(a,b) = (a.s > b.s) || (a.s == b.s && a.i < b.i)  — total order (idx unique)
  for (int k = 2; k <= NN; k <<= 1){
    bool up = ((t & k) == 0);
    // cross-wave stages via LDS
    for (int j = k >> 1; j >= 64; j >>= 1){
      ss[t] = s; si[t] = idx;
      __syncthreads();
      double os = ss[t ^ j]; int oi = si[t ^ j];
      bool first = ((t & j) == 0);
      bool cmp = (s > os) || (s == os && idx < oi);
      bool keep = (cmp == (first == up));
      if (!keep){ s = os; idx = oi; }
      __syncthreads();
    }
    // in-wave stages via register shuffles
    #pragma unroll
    for (int j = 32; j > 0; j >>= 1){
      if (j <= (k >> 1)){
        double os = __shfl_xor(s, j, 64);
        int    oi = __shfl_xor(idx, j, 64);
        bool first = ((t & j) == 0);
        bool cmp = (s > os) || (s == os && idx < oi);
        bool keep = (cmp == (first == up));
        if (!keep){ s = os; idx = oi; }
      }
    }
  }
  __syncthreads();
  perm[b*NN + t] = idx;
  s1s[b*NN + t] = l1[idx];  // sorted-order a1 dot
  s2s[b*NN + t] = l2[idx];  // sorted-order a2 dot
}

// ---------------- K2: passA, 16 lanes = 1 window: gk, rank, colsum partial ----------------
__global__ __launch_bounds__(256) void k_passA(const float* __restrict__ x,
    const int* __restrict__ perm, const double* __restrict__ s1s,
    const double* __restrict__ s2s, double* __restrict__ gkd,
    unsigned char* __restrict__ rank8, double* __restrict__ partial){
  int b = blockIdx.y, ch = blockIdx.x, tid = threadIdx.x;
  int i0 = ch*WPB;
  int nwin  = min(WPB, RES - i0);
  int nrows = min(ROWS, NN - i0);
  __shared__ float  xs[ROWS*PITCH];   // ~8.2 KB
  __shared__ int    pg[ROWS];
  __shared__ double wred[4][FS];

  if (tid < nrows) pg[tid] = perm[b*NN + i0 + tid];
  __syncthreads();
  for (int u = tid; u < nrows*16; u += 256){
    int r = u >> 4, seg = u & 15;
    float4 v = ((const float4*)(x + (size_t)(b*NN + pg[r])*CC))[seg];
    float2* dst = (float2*)&xs[r*PITCH + seg*4];
    dst[0] = make_float2(v.x, v.y);
    dst[1] = make_float2(v.z, v.w);
  }
  __syncthreads();

  int w = tid >> 4, j = tid & 15;
  int lane = tid & 63, gbase = lane & 48, wv = tid >> 6;
  bool act = (w < nwin);
  int i = i0 + w;

  // squared distance (f64, sequential c order like the reference)
  double sq = 0.0;
  const float* rs = &xs[w*PITCH];
  const float* rd = &xs[(w+j)*PITCH];
  #pragma unroll
  for (int c2=0;c2<CC/2;c2++){
    float2 a  = *(const float2*)&rs[2*c2];
    float2 bb = *(const float2*)&rd[2*c2];
    double d0 = (double)a.x - (double)bb.x;
    double d1v= (double)a.y - (double)bb.y;
    sq += d0*d0;
    sq += d1v*d1v;
  }
  double d   = (sq > 0.0) ? sqrt(sq) : 0.0;     // safe_norm
  double gkv = exp(-d*0.5) - 1e-20;

  // window softmax term (f64, max-subtracted)
  int drow = min(i + j, NN-1);                   // clamp only hits inactive lanes
  double smt = s1s[b*NN + i] + s2s[b*NN + drow];
  double m = smt;
  #pragma unroll
  for (int off=8; off; off>>=1) m = fmax(m, __shfl_xor(m, off, 16));
  double em = exp(smt - m);
  double ssum = em;
  #pragma unroll
  for (int off=8; off; off>>=1) ssum += __shfl_xor(ssum, off, 16);
  double smn = em / ssum;

  // rank within window: #(k before j) under (gk desc, idx asc)
  int rank = 0;
  #pragma unroll
  for (int k=0;k<16;k++){
    double gkk = __shfl(gkv, gbase + k, 64);
    rank += ((gkk > gkv) || (gkk == gkv && k < j)) ? 1 : 0;
  }

  if (act){
    size_t base = ((size_t)b*RES + i)*FS;
    gkd[base + j]   = gkv;
    rank8[base + j] = (unsigned char)rank;
  }

  // scatter softmax term to its rank lane, then sum windows (deterministic order)
  double contrib = act ? smn : 0.0;
  double srt = wave_push_f64(contrib, gbase + rank);
  srt += __shfl_xor(srt, 16, 64);
  srt += __shfl_xor(srt, 32, 64);
  if (lane < FS) wred[wv][lane] = srt;
  __syncthreads();
  if (tid < FS){
    partial[((size_t)b*NCH + ch)*FS + tid] =
        wred[0][tid] + wred[1][tid] + wred[2][tid] + wred[3][tid];
  }
}

// ---------------- K3: serial gumbel: 1 thread = 1 window. colsum (redundant per block),
//                      15 independent threefry chains, np-order sums, no cross-lane ops.
//                      grid = (2, BB) x 256 ----------------
__global__ __launch_bounds__(256) void k_gumbel(const double* __restrict__ gkd,
    const unsigned char* __restrict__ rank8, const double* __restrict__ partial,
    const int* __restrict__ epoch_p, float* __restrict__ shifted_out,
    int* __restrict__ delta){
  int b = blockIdx.y, tid = threadIdx.x;
  int win = blockIdx.x*GW2 + tid;
  __shared__ double pl[NCH*FS];        // 4 KB
  __shared__ double cs[FS];
  __shared__ double glds[256*17];      // 34 KB: private padded slice per thread

  for (int u = tid; u < NCH*FS; u += 256) pl[u] = partial[(size_t)b*NCH*FS + u];
  __syncthreads();
  if (tid < FS){
    double a = 0.0;
    #pragma unroll
    for (int ch=0; ch<NCH; ch++) a += pl[ch*FS + tid];   // same seq order as before
    cs[tid] = a;
  }
  __syncthreads();

  if (win >= RES) return;
  double tau = 10.0 * pow(0.01, (double)epoch_p[0] / 100.0);
  size_t base = ((size_t)b*RES + win)*FS;

  // load gk row (128B contiguous per thread -> 8KB outstanding per wave)
  double gk[FS];
  #pragma unroll
  for (int j=0;j<FS;j++) gk[j] = gkd[base + j];

  // z values (15 independent threefry chains), serial max (np semantics)
  double z[FS];
  z[0] = 0.0;  // placeholder, excluded
  #pragma unroll
  for (int s=1;s<FS;s++){
    double g = (double)gumbel_at_f32((unsigned)(base + (unsigned)s));
    z[s] = (g + cs[s]) / tau;
  }
  double m = z[1];
  #pragma unroll
  for (int s=2;s<FS;s++) m = fmax(m, z[s]);

  // e and ssum in np sequential order
  double e[FS]; double ssum = 0.0;
  e[0] = 0.0;
  #pragma unroll
  for (int s=1;s<FS;s++){ e[s] = exp(z[s] - m); ssum += e[s]; }

  // scatter gk by rank into private LDS slice: glds[rank[j]] = gk[j]  => gk_sort
  int base17 = tid*17;
  #pragma unroll
  for (int j=0;j<FS;j++){
    int rk = (int)rank8[base + j];
    glds[base17 + rk] = gk[j];
  }
  // ths = sum_s gk_sort[s] * (e[s]/ssum)  — exactly np's s-ascending order
  double ths = 0.0;
  #pragma unroll
  for (int s=0;s<FS;s++){
    ths += glds[base17 + s] * (e[s] / ssum);
  }

  // shifted + argmin (strict <, first-min wins), serial
  double bv = 0.0; int bj = 1;
  #pragma unroll
  for (int j=0;j<FS;j++){
    double shv = fmax(gk[j] - ths, 0.0);
    shifted_out[base + j] = (float)shv;
    if (j == 1){ bv = shv; bj = 1; }
    else if (j > 1 && shv < bv){ bv = shv; bj = j; }
  }
  delta[b*RES + win] = bj;
}

// ---------------- K4: per-graph chain (pointer doubling) + pooled gather ----------------
__global__ __launch_bounds__(256) void k_chainpool(const int* __restrict__ delta,
    const int* __restrict__ perm, const float* __restrict__ x,
    float* __restrict__ piv_out, float* __restrict__ pooled){
  int b = blockIdx.x, tid = threadIdx.x;
  __shared__ int tbl[8][512];    // 16 KB
  __shared__ int pivS[MAXP];

  for (int i = tid; i < 512; i += 256){
    int v;
    if (i < RES){ v = i + delta[b*RES + i]; if (v > RES) v = RES; }
    else v = RES;                 // absorbing sentinel
    tbl[0][i] = v;
  }
  __syncthreads();
  #pragma unroll
  for (int k=1;k<8;k++){
    int v0 = tbl[k-1][tid];
    int v1 = tbl[k-1][tid+256];
    tbl[k][tid]     = tbl[k-1][v0];
    tbl[k][tid+256] = tbl[k-1][v1];
    __syncthreads();
  }
  {
    int p = 0;
    #pragma unroll
    for (int k=0;k<8;k++) if ((tid>>k)&1) p = tbl[k][p];
    int piv = (p < RES) ? p : -1;
    pivS[tid] = piv;
    piv_out[b*MAXP + tid] = (float)piv;
  }
  __syncthreads();

  // pooled gather (masked)
  for (int u = tid; u < MAXP*16; u += 256){
    int bp = u >> 4, seg = u & 15;
    int piv = pivS[bp];
    float4 v = make_float4(0.f,0.f,0.f,0.f);
    if (piv >= 0){
      int src = perm[b*NN + piv];
      v = ((const float4*)(x + (size_t)(b*NN + src)*CC))[seg];
    }
    ((float4*)pooled)[(size_t)(b*MAXP + bp)*16 + seg] = v;
  }
}

extern "C" void kernel_launch(void* const* d_in, const int* in_sizes, int n_in,
                              void* d_out, int out_size, void* d_ws, size_t ws_size,
                              hipStream_t stream) {
  (void)in_sizes; (void)n_in; (void)out_size; (void)ws_size;
  const float* x    = (const float*)d_in[0];
  const float* w    = (const float*)d_in[1];
  const float* bsc  = (const float*)d_in[2];
  const float* att  = (const float*)d_in[3];
  const int*   epch = (const int*)d_in[5];

  // workspace layout (~11.3 MiB), f64 first for alignment
  double* s1s     = (double*)d_ws;               // BN
  double* s2s     = s1s + BN;                    // BN
  double* gkd     = s2s + BN;                    // GT
  double* partial = gkd + GT;                    // BB*NCH*FS
  int*    perm    = (int*)(partial + (size_t)BB*NCH*FS); // BN
  int*    delta   = perm + BN;                   // BB*RES
  unsigned char* rank8 = (unsigned char*)(delta + BB*RES); // GT bytes

  float* out_pooled  = (float*)d_out;                   // B*MAXP*C
  float* out_shifted = out_pooled + BB*MAXP*CC;         // B*RES*FS
  float* out_piv     = out_shifted + (size_t)BB*RES*FS; // B*MAXP (as float)

  k_scoresort<<<BB, NN, 0, stream>>>(x, w, bsc, att, s1s, s2s, perm);
  k_passA    <<<dim3(NCH, BB), 256, 0, stream>>>(x, perm, s1s, s2s, gkd, rank8, partial);
  k_gumbel   <<<dim3((RES + GW2 - 1)/GW2, BB), GW2, 0, stream>>>(gkd, rank8, partial, epch, out_shifted, delta);
  k_chainpool<<<BB, 256, 0, stream>>>(delta, perm, x, out_piv, out_pooled);
}